// Round 3
// baseline (1169.917 us; speedup 1.0000x reference)
//
#include <hip/hip_runtime.h>

#define EPS_BN 1e-5f
#define C 128
#define CG 32     // float4 groups per 128-channel row
#define CAP 6144  // per-bucket edge capacity in LDS (mean 4092, sigma ~64)

// ---------------- init: zero BN accumulators + bucket counts ------------------
__global__ void k_init(float* __restrict__ sums, int* __restrict__ bcnt, int NB) {
  int i = blockIdx.x * blockDim.x + threadIdx.x;
  if (i < 256) sums[i] = 0.0f;
  if (i < NB) bcnt[i] = 0;
}

// ---------------- column sum / sumsq over rows --------------------------------
__global__ void k_stats(const float4* __restrict__ x4, float* __restrict__ sums, int n) {
  __shared__ float4 s_s[256];
  __shared__ float4 s_q[256];
  int t = threadIdx.x;
  int cg = t & 31;
  int rl = t >> 5;
  float4 s = make_float4(0.f, 0.f, 0.f, 0.f);
  float4 q = make_float4(0.f, 0.f, 0.f, 0.f);
  for (int r = blockIdx.x * 8 + rl; r < n; r += gridDim.x * 8) {
    float4 v = x4[(size_t)r * CG + cg];
    s.x += v.x; s.y += v.y; s.z += v.z; s.w += v.w;
    q.x += v.x * v.x; q.y += v.y * v.y; q.z += v.z * v.z; q.w += v.w * v.w;
  }
  s_s[t] = s; s_q[t] = q;
  __syncthreads();
  if (t < 32) {
    for (int j = 1; j < 8; ++j) {
      float4 a = s_s[t + 32 * j];
      float4 b = s_q[t + 32 * j];
      s.x += a.x; s.y += a.y; s.z += a.z; s.w += a.w;
      q.x += b.x; q.y += b.y; q.z += b.z; q.w += b.w;
    }
    atomicAdd(&sums[t * 4 + 0], s.x);
    atomicAdd(&sums[t * 4 + 1], s.y);
    atomicAdd(&sums[t * 4 + 2], s.z);
    atomicAdd(&sums[t * 4 + 3], s.w);
    atomicAdd(&sums[C + t * 4 + 0], q.x);
    atomicAdd(&sums[C + t * 4 + 1], q.y);
    atomicAdd(&sums[C + t * 4 + 2], q.z);
    atomicAdd(&sums[C + t * 4 + 3], q.w);
  }
}

// ---------------- fold BN into per-channel scale/shift ------------------------
__global__ void k_finalize(const float* __restrict__ sums,
                           const float* __restrict__ gamma,
                           const float* __restrict__ beta,
                           float* __restrict__ scale, float* __restrict__ shift,
                           int n) {
  int c = threadIdx.x;
  if (c < C) {
    float inv_n = 1.0f / (float)n;
    float mean = sums[c] * inv_n;
    float var = sums[C + c] * inv_n - mean * mean;
    float rstd = rsqrtf(var + EPS_BN);
    float sc = gamma[c] * rstd;
    scale[c] = sc;
    shift[c] = beta[c] - mean * sc;
  }
}

// ---------------- binA: per-bucket edge histogram (LDS-staged) ----------------
__global__ void k_binA(const int* __restrict__ col, int* __restrict__ bcnt,
                       int E, int NB) {
  __shared__ int h[800];
  for (int i = threadIdx.x; i < NB; i += 256) h[i] = 0;
  __syncthreads();
  for (int e = blockIdx.x * 256 + threadIdx.x; e < E; e += gridDim.x * 256)
    atomicAdd(&h[col[e] >> 7], 1);
  __syncthreads();
  for (int i = threadIdx.x; i < NB; i += 256)
    if (h[i]) atomicAdd(&bcnt[i], h[i]);
}

// ---------------- scanB: exclusive scan of bucket counts ----------------------
__global__ void k_scanB(const int* __restrict__ bcnt, int* __restrict__ boffs,
                        int* __restrict__ cursors, int NB, int E) {
  __shared__ int sh[1024];
  int t = threadIdx.x;
  int v = (t < NB) ? bcnt[t] : 0;
  sh[t] = v;
  __syncthreads();
  for (int off = 1; off < 1024; off <<= 1) {
    int a = (t >= off) ? sh[t - off] : 0;
    __syncthreads();
    sh[t] += a;
    __syncthreads();
  }
  if (t < NB) {
    int o = sh[t] - v;
    boffs[t] = o;
    cursors[t] = o;
  }
  if (t == 0) boffs[NB] = E;
}

// ---------------- binB: scatter packed (local,row) into bucket regions --------
__global__ void k_binB(const int* __restrict__ row, const int* __restrict__ col,
                       int* __restrict__ cursors, unsigned* __restrict__ binned,
                       int E) {
  for (int e = blockIdx.x * blockDim.x + threadIdx.x; e < E;
       e += gridDim.x * blockDim.x) {
    int c = col[e];
    int pos = atomicAdd(&cursors[c >> 7], 1);
    binned[pos] = ((unsigned)(c & 127) << 17) | (unsigned)row[e];
  }
}

// ---------------- C1: per-bucket degree count (LDS atomics) -> dis ------------
__global__ void k_C1(const unsigned* __restrict__ binned,
                     const int* __restrict__ boffs, float* __restrict__ dis,
                     int n) {
  __shared__ int cnt[128];
  int b = blockIdx.x, t = threadIdx.x;
  if (t < 128) cnt[t] = 0;
  __syncthreads();
  int s = boffs[b], tend = boffs[b + 1];
  for (int i = s + t; i < tend; i += 256) atomicAdd(&cnt[binned[i] >> 17], 1);
  __syncthreads();
  int node = b * 128 + t;
  if (t < 128 && node < n) dis[node] = rsqrtf((float)(cnt[t] + 1));
}

// ---------------- C2: LDS-CSR build + per-node wave gather-reduce -------------
// out[c] = dis[c] * ( scale * sum_e x[r]*dis[r]  +  shift * sum_e dis[r] )
__global__ __launch_bounds__(256) void k_C2(
    const float2* __restrict__ x2, const unsigned* __restrict__ binned,
    const int* __restrict__ boffs, const float* __restrict__ dis,
    const float2* __restrict__ scale2, const float2* __restrict__ shift2,
    float2* __restrict__ out2, int n) {
  __shared__ int cnt[128];
  __shared__ int offs[128];
  __shared__ int cur[128];
  __shared__ int scn[128];
  __shared__ unsigned list[CAP];
  int b = blockIdx.x, t = threadIdx.x;
  if (t < 128) cnt[t] = 0;
  __syncthreads();
  int s = boffs[b], tend = boffs[b + 1];
  // phase 1: per-node degree count
  for (int i = s + t; i < tend; i += 256) atomicAdd(&cnt[binned[i] >> 17], 1);
  __syncthreads();
  // phase 2: exclusive scan of 128 counts
  if (t < 128) scn[t] = cnt[t];
  __syncthreads();
  for (int off = 1; off < 128; off <<= 1) {
    int a = (t >= off && t < 128) ? scn[t - off] : 0;
    __syncthreads();
    if (t < 128) scn[t] += a;
    __syncthreads();
  }
  if (t < 128) {
    offs[t] = scn[t] - cnt[t];
    cur[t] = scn[t] - cnt[t];
  }
  __syncthreads();
  // phase 3: fill LDS CSR
  for (int i = s + t; i < tend; i += 256) {
    unsigned e = binned[i];
    int pos = atomicAdd(&cur[e >> 17], 1);
    if (pos < CAP) list[pos] = e & 0x1FFFFu;
  }
  __syncthreads();
  // phase 4: gather-reduce, one wave per node
  int w = t >> 6, lane = t & 63;
  int bn = min(128, n - b * 128);
  for (int l = w; l < bn; l += 4) {
    int deg = cnt[l], base = offs[l];
    float2 a0 = make_float2(0.f, 0.f), a1 = make_float2(0.f, 0.f);
    float sd0 = 0.f, sd1 = 0.f;
    int i = 0;
    for (; i + 1 < deg; i += 2) {
      int r0 = list[base + i], r1 = list[base + i + 1];
      float d0 = dis[r0], d1 = dis[r1];
      float2 v0 = x2[(size_t)r0 * 64 + lane];
      float2 v1 = x2[(size_t)r1 * 64 + lane];
      a0.x += v0.x * d0; a0.y += v0.y * d0; sd0 += d0;
      a1.x += v1.x * d1; a1.y += v1.y * d1; sd1 += d1;
    }
    if (i < deg) {
      int r = list[base + i];
      float d = dis[r];
      float2 v = x2[(size_t)r * 64 + lane];
      a0.x += v.x * d; a0.y += v.y * d; sd0 += d;
    }
    int node = b * 128 + l;
    float dc = dis[node];
    float2 sc = scale2[lane], sh = shift2[lane];
    float sd = sd0 + sd1;
    float2 o;
    o.x = dc * ((a0.x + a1.x) * sc.x + sd * sh.x);
    o.y = dc * ((a0.y + a1.y) * sc.y + sd * sh.y);
    out2[(size_t)node * 64 + lane] = o;
  }
}

// ---------------- in-place GEMM: out = relu((g + xn*invdeg) @ W + b) ----------
__global__ __launch_bounds__(256) void k_gemm(float* __restrict__ out,
                        const float4* __restrict__ x4,
                        const float* __restrict__ W,
                        const float* __restrict__ bias,
                        const float* __restrict__ scale,
                        const float* __restrict__ shift,
                        const float* __restrict__ dis, int n) {
  __shared__ float sW[64 * C];
  __shared__ float sG[32 * C];
  int t = threadIdx.x;
  int rowBase = blockIdx.x * 32;

  const float4* scale4 = (const float4*)scale;
  const float4* shift4 = (const float4*)shift;
  float4* sG4 = (float4*)sG;
  float4* sW4 = (float4*)sW;
  const float4* W4 = (const float4*)W;
  const float4* out4 = (const float4*)out;

  for (int i = t; i < 32 * CG; i += 256) {
    int r = i >> 5, g = i & 31;
    int rw = rowBase + r;
    float4 acc = make_float4(0.f, 0.f, 0.f, 0.f);
    if (rw < n) {
      acc = out4[(size_t)rw * CG + g];
      float4 xv = x4[(size_t)rw * CG + g];
      float d = dis[rw];
      float inv = d * d;
      float4 sc = scale4[g];
      float4 sh = shift4[g];
      acc.x += (xv.x * sc.x + sh.x) * inv;
      acc.y += (xv.y * sc.y + sh.y) * inv;
      acc.z += (xv.z * sc.z + sh.z) * inv;
      acc.w += (xv.w * sc.w + sh.w) * inv;
    }
    sG4[i] = acc;
  }

  int tx = t & 127;
  int ty = t >> 7;
  float acc[16];
#pragma unroll
  for (int i = 0; i < 16; ++i) acc[i] = 0.f;

  for (int kc = 0; kc < 2; ++kc) {
    for (int i = t; i < 64 * C / 4; i += 256) sW4[i] = W4[kc * 2048 + i];
    __syncthreads();
#pragma unroll 4
    for (int k = 0; k < 64; ++k) {
      float w = sW[k * C + tx];
#pragma unroll
      for (int rr = 0; rr < 16; ++rr)
        acc[rr] += sG[(rr * 2 + ty) * C + kc * 64 + k] * w;
    }
    __syncthreads();
  }

  float bv = bias[tx];
#pragma unroll
  for (int rr = 0; rr < 16; ++rr) {
    int rw = rowBase + rr * 2 + ty;
    if (rw < n) {
      float o = acc[rr] + bv;
      out[(size_t)rw * C + tx] = o > 0.f ? o : 0.f;
    }
  }
}

extern "C" void kernel_launch(void* const* d_in, const int* in_sizes, int n_in,
                              void* d_out, int out_size, void* d_ws, size_t ws_size,
                              hipStream_t stream) {
  const float* x = (const float*)d_in[0];
  const int* edge = (const int*)d_in[1];
  const float* gamma = (const float*)d_in[2];
  const float* beta = (const float*)d_in[3];
  const float* W = (const float*)d_in[4];
  const float* bias = (const float*)d_in[5];
  float* out = (float*)d_out;

  int n = in_sizes[0] / C;
  int E = in_sizes[1] / 2;
  int NB = (n + 127) / 128;  // buckets of 128 dst nodes (<=1024)

  float* ws = (float*)d_ws;
  float* sums = ws;                      // 256 f
  float* scale = ws + 256;               // 128 f
  float* shift = ws + 384;               // 128 f
  float* dis = ws + 512;                 // n f
  int* bcnt = (int*)(ws + 512 + n);      // NB i
  int* boffs = bcnt + NB;                // NB+1 i
  int* cursors = boffs + NB + 1;         // NB i
  unsigned* binned = (unsigned*)(cursors + NB);  // E u32

  k_init<<<4, 256, 0, stream>>>(sums, bcnt, NB);
  k_stats<<<256, 256, 0, stream>>>((const float4*)x, sums, n);
  k_finalize<<<1, 128, 0, stream>>>(sums, gamma, beta, scale, shift, n);
  k_binA<<<256, 256, 0, stream>>>(edge + E, bcnt, E, NB);
  k_scanB<<<1, 1024, 0, stream>>>(bcnt, boffs, cursors, NB, E);
  k_binB<<<2048, 256, 0, stream>>>(edge, edge + E, cursors, binned, E);
  k_C1<<<NB, 256, 0, stream>>>(binned, boffs, dis, n);
  k_C2<<<NB, 256, 0, stream>>>((const float2*)x, binned, boffs, dis,
                               (const float2*)scale, (const float2*)shift,
                               (float2*)out, n);
  k_gemm<<<(n + 31) / 32, 256, 0, stream>>>(out, (const float4*)x, W, bias,
                                            scale, shift, dis, n);
}

// Round 4
// 455.190 us; speedup vs baseline: 2.5702x; 2.5702x over previous
//
#include <hip/hip_runtime.h>

#define EPS_BN 1e-5f
#define C 128
#define CG 32     // float4 groups per 128-channel row
#define CAP 6144  // per-bucket edge capacity in LDS (mean 4092, sigma ~64)
#define NBLK 256  // partition blocks

// ---------------- init: zero BN accumulators ----------------------------------
__global__ void k_init(float* __restrict__ sums) {
  int i = blockIdx.x * blockDim.x + threadIdx.x;
  if (i < 256) sums[i] = 0.0f;
}

// ---------------- column sum / sumsq over rows --------------------------------
__global__ void k_stats(const float4* __restrict__ x4, float* __restrict__ sums, int n) {
  __shared__ float4 s_s[256];
  __shared__ float4 s_q[256];
  int t = threadIdx.x;
  int cg = t & 31;
  int rl = t >> 5;
  float4 s = make_float4(0.f, 0.f, 0.f, 0.f);
  float4 q = make_float4(0.f, 0.f, 0.f, 0.f);
  for (int r = blockIdx.x * 8 + rl; r < n; r += gridDim.x * 8) {
    float4 v = x4[(size_t)r * CG + cg];
    s.x += v.x; s.y += v.y; s.z += v.z; s.w += v.w;
    q.x += v.x * v.x; q.y += v.y * v.y; q.z += v.z * v.z; q.w += v.w * v.w;
  }
  s_s[t] = s; s_q[t] = q;
  __syncthreads();
  if (t < 32) {
    for (int j = 1; j < 8; ++j) {
      float4 a = s_s[t + 32 * j];
      float4 b = s_q[t + 32 * j];
      s.x += a.x; s.y += a.y; s.z += a.z; s.w += a.w;
      q.x += b.x; q.y += b.y; q.z += b.z; q.w += b.w;
    }
    atomicAdd(&sums[t * 4 + 0], s.x);
    atomicAdd(&sums[t * 4 + 1], s.y);
    atomicAdd(&sums[t * 4 + 2], s.z);
    atomicAdd(&sums[t * 4 + 3], s.w);
    atomicAdd(&sums[C + t * 4 + 0], q.x);
    atomicAdd(&sums[C + t * 4 + 1], q.y);
    atomicAdd(&sums[C + t * 4 + 2], q.z);
    atomicAdd(&sums[C + t * 4 + 3], q.w);
  }
}

// ---------------- fold BN into per-channel scale/shift ------------------------
__global__ void k_finalize(const float* __restrict__ sums,
                           const float* __restrict__ gamma,
                           const float* __restrict__ beta,
                           float* __restrict__ scale, float* __restrict__ shift,
                           int n) {
  int c = threadIdx.x;
  if (c < C) {
    float inv_n = 1.0f / (float)n;
    float mean = sums[c] * inv_n;
    float var = sums[C + c] * inv_n - mean * mean;
    float rstd = rsqrtf(var + EPS_BN);
    float sc = gamma[c] * rstd;
    scale[c] = sc;
    shift[c] = beta[c] - mean * sc;
  }
}

// ---------------- pass 1: per-block bucket histogram --------------------------
__global__ void k_hist(const int* __restrict__ col, int* __restrict__ histG,
                       int E, int NB, int chunk) {
  __shared__ int h[800];
  int b = blockIdx.x, t = threadIdx.x;
  for (int i = t; i < NB; i += 256) h[i] = 0;
  __syncthreads();
  int s = b * chunk, eend = min(E, s + chunk);
  for (int e = s + t; e < eend; e += 256) atomicAdd(&h[col[e] >> 7], 1);
  __syncthreads();
  for (int i = t; i < NB; i += 256) histG[b * NB + i] = h[i];
}

// ---------------- pass 2a: per-bucket scan over NBLK block counts -------------
__global__ void k_scanH(int* __restrict__ histG, int* __restrict__ btot, int NB) {
  __shared__ int sh[NBLK];
  int q = blockIdx.x, t = threadIdx.x;
  int v = histG[t * NB + q];
  sh[t] = v;
  __syncthreads();
  for (int off = 1; off < NBLK; off <<= 1) {
    int a = (t >= off) ? sh[t - off] : 0;
    __syncthreads();
    sh[t] += a;
    __syncthreads();
  }
  histG[t * NB + q] = sh[t] - v;  // exclusive within bucket
  if (t == NBLK - 1) btot[q] = sh[t];
}

// ---------------- pass 2b: scan bucket totals -> boffs ------------------------
__global__ void k_scanB(const int* __restrict__ btot, int* __restrict__ boffs,
                        int NB, int E) {
  __shared__ int sh[1024];
  int t = threadIdx.x;
  int v = (t < NB) ? btot[t] : 0;
  sh[t] = v;
  __syncthreads();
  for (int off = 1; off < 1024; off <<= 1) {
    int a = (t >= off) ? sh[t - off] : 0;
    __syncthreads();
    sh[t] += a;
    __syncthreads();
  }
  if (t < NB) boffs[t] = sh[t] - v;
  if (t == 0) boffs[NB] = E;
}

// ---------------- pass 3: scatter into disjoint per-(block,bucket) runs ------
__global__ void k_part(const int* __restrict__ row, const int* __restrict__ col,
                       const int* __restrict__ histG, const int* __restrict__ boffs,
                       unsigned* __restrict__ binned, int E, int NB, int chunk) {
  __shared__ int cur[800];
  int b = blockIdx.x, t = threadIdx.x;
  for (int i = t; i < NB; i += 256) cur[i] = boffs[i] + histG[b * NB + i];
  __syncthreads();
  int s = b * chunk, eend = min(E, s + chunk);
  for (int e = s + t; e < eend; e += 256) {
    int c = col[e];
    int pos = atomicAdd(&cur[c >> 7], 1);
    binned[pos] = ((unsigned)(c & 127) << 17) | (unsigned)row[e];
  }
}

// ---------------- C1: per-bucket degree count (LDS atomics) -> dis ------------
__global__ void k_C1(const unsigned* __restrict__ binned,
                     const int* __restrict__ boffs, float* __restrict__ dis,
                     int n) {
  __shared__ int cnt[128];
  int b = blockIdx.x, t = threadIdx.x;
  if (t < 128) cnt[t] = 0;
  __syncthreads();
  int s = boffs[b], tend = boffs[b + 1];
  for (int i = s + t; i < tend; i += 256) atomicAdd(&cnt[binned[i] >> 17], 1);
  __syncthreads();
  int node = b * 128 + t;
  if (t < 128 && node < n) dis[node] = rsqrtf((float)(cnt[t] + 1));
}

// ---------------- C2: LDS-CSR build + per-node wave gather-reduce -------------
// out[c] = dis[c] * ( scale * sum_e x[r]*dis[r]  +  shift * sum_e dis[r] )
__global__ __launch_bounds__(512) void k_C2(
    const float2* __restrict__ x2, const unsigned* __restrict__ binned,
    const int* __restrict__ boffs, const float* __restrict__ dis,
    const float2* __restrict__ scale2, const float2* __restrict__ shift2,
    float2* __restrict__ out2, int n) {
  __shared__ int cnt[128];
  __shared__ int offs[128];
  __shared__ int cur[128];
  __shared__ int scn[128];
  __shared__ unsigned list[CAP];
  int b = blockIdx.x, t = threadIdx.x;
  if (t < 128) cnt[t] = 0;
  __syncthreads();
  int s = boffs[b], tend = boffs[b + 1];
  // phase 1: per-node degree count
  for (int i = s + t; i < tend; i += 512) atomicAdd(&cnt[binned[i] >> 17], 1);
  __syncthreads();
  // phase 2: exclusive scan of 128 counts
  if (t < 128) scn[t] = cnt[t];
  __syncthreads();
  for (int off = 1; off < 128; off <<= 1) {
    int a = (t >= off && t < 128) ? scn[t - off] : 0;
    __syncthreads();
    if (t < 128) scn[t] += a;
    __syncthreads();
  }
  if (t < 128) {
    offs[t] = scn[t] - cnt[t];
    cur[t] = scn[t] - cnt[t];
  }
  __syncthreads();
  // phase 3: fill LDS CSR
  for (int i = s + t; i < tend; i += 512) {
    unsigned e = binned[i];
    int pos = atomicAdd(&cur[e >> 17], 1);
    if (pos < CAP) list[pos] = e & 0x1FFFFu;
  }
  __syncthreads();
  // phase 4: gather-reduce, one wave per node
  int w = t >> 6, lane = t & 63;
  int bn = min(128, n - b * 128);
  for (int l = w; l < bn; l += 8) {
    int deg = cnt[l], base = offs[l];
    float2 a0 = make_float2(0.f, 0.f), a1 = make_float2(0.f, 0.f);
    float sd0 = 0.f, sd1 = 0.f;
    int i = 0;
    for (; i + 1 < deg; i += 2) {
      int r0 = list[base + i], r1 = list[base + i + 1];
      float d0 = dis[r0], d1 = dis[r1];
      float2 v0 = x2[(size_t)r0 * 64 + lane];
      float2 v1 = x2[(size_t)r1 * 64 + lane];
      a0.x += v0.x * d0; a0.y += v0.y * d0; sd0 += d0;
      a1.x += v1.x * d1; a1.y += v1.y * d1; sd1 += d1;
    }
    if (i < deg) {
      int r = list[base + i];
      float d = dis[r];
      float2 v = x2[(size_t)r * 64 + lane];
      a0.x += v.x * d; a0.y += v.y * d; sd0 += d;
    }
    int node = b * 128 + l;
    float dc = dis[node];
    float2 sc = scale2[lane], sh = shift2[lane];
    float sd = sd0 + sd1;
    float2 o;
    o.x = dc * ((a0.x + a1.x) * sc.x + sd * sh.x);
    o.y = dc * ((a0.y + a1.y) * sc.y + sd * sh.y);
    out2[(size_t)node * 64 + lane] = o;
  }
}

// ---------------- in-place GEMM: out = relu((g + xn*invdeg) @ W + b) ----------
__global__ __launch_bounds__(256) void k_gemm(float* __restrict__ out,
                        const float4* __restrict__ x4,
                        const float* __restrict__ W,
                        const float* __restrict__ bias,
                        const float* __restrict__ scale,
                        const float* __restrict__ shift,
                        const float* __restrict__ dis, int n) {
  __shared__ float sW[64 * C];
  __shared__ float sG[32 * C];
  int t = threadIdx.x;
  int rowBase = blockIdx.x * 32;

  const float4* scale4 = (const float4*)scale;
  const float4* shift4 = (const float4*)shift;
  float4* sG4 = (float4*)sG;
  float4* sW4 = (float4*)sW;
  const float4* W4 = (const float4*)W;
  const float4* out4 = (const float4*)out;

  for (int i = t; i < 32 * CG; i += 256) {
    int r = i >> 5, g = i & 31;
    int rw = rowBase + r;
    float4 acc = make_float4(0.f, 0.f, 0.f, 0.f);
    if (rw < n) {
      acc = out4[(size_t)rw * CG + g];
      float4 xv = x4[(size_t)rw * CG + g];
      float d = dis[rw];
      float inv = d * d;
      float4 sc = scale4[g];
      float4 sh = shift4[g];
      acc.x += (xv.x * sc.x + sh.x) * inv;
      acc.y += (xv.y * sc.y + sh.y) * inv;
      acc.z += (xv.z * sc.z + sh.z) * inv;
      acc.w += (xv.w * sc.w + sh.w) * inv;
    }
    sG4[i] = acc;
  }

  int tx = t & 127;
  int ty = t >> 7;
  float acc[16];
#pragma unroll
  for (int i = 0; i < 16; ++i) acc[i] = 0.f;

  for (int kc = 0; kc < 2; ++kc) {
    for (int i = t; i < 64 * C / 4; i += 256) sW4[i] = W4[kc * 2048 + i];
    __syncthreads();
#pragma unroll 4
    for (int k = 0; k < 64; ++k) {
      float w = sW[k * C + tx];
#pragma unroll
      for (int rr = 0; rr < 16; ++rr)
        acc[rr] += sG[(rr * 2 + ty) * C + kc * 64 + k] * w;
    }
    __syncthreads();
  }

  float bv = bias[tx];
#pragma unroll
  for (int rr = 0; rr < 16; ++rr) {
    int rw = rowBase + rr * 2 + ty;
    if (rw < n) {
      float o = acc[rr] + bv;
      out[(size_t)rw * C + tx] = o > 0.f ? o : 0.f;
    }
  }
}

extern "C" void kernel_launch(void* const* d_in, const int* in_sizes, int n_in,
                              void* d_out, int out_size, void* d_ws, size_t ws_size,
                              hipStream_t stream) {
  const float* x = (const float*)d_in[0];
  const int* edge = (const int*)d_in[1];
  const float* gamma = (const float*)d_in[2];
  const float* beta = (const float*)d_in[3];
  const float* W = (const float*)d_in[4];
  const float* bias = (const float*)d_in[5];
  float* out = (float*)d_out;

  int n = in_sizes[0] / C;
  int E = in_sizes[1] / 2;
  int NB = (n + 127) / 128;           // buckets of 128 dst nodes (<=800)
  int chunk = (E + NBLK - 1) / NBLK;  // edges per partition block

  float* ws = (float*)d_ws;
  float* sums = ws;                      // 256 f
  float* scale = ws + 256;               // 128 f
  float* shift = ws + 384;               // 128 f
  float* dis = ws + 512;                 // n f
  int* btot = (int*)(ws + 512 + n);      // NB i
  int* boffs = btot + NB;                // NB+1 i
  int* histG = boffs + NB + 1;           // NBLK*NB i
  unsigned* binned = (unsigned*)(histG + NBLK * NB);  // E u32

  k_init<<<1, 256, 0, stream>>>(sums);
  k_stats<<<256, 256, 0, stream>>>((const float4*)x, sums, n);
  k_finalize<<<1, 128, 0, stream>>>(sums, gamma, beta, scale, shift, n);
  k_hist<<<NBLK, 256, 0, stream>>>(edge + E, histG, E, NB, chunk);
  k_scanH<<<NB, NBLK, 0, stream>>>(histG, btot, NB);
  k_scanB<<<1, 1024, 0, stream>>>(btot, boffs, NB, E);
  k_part<<<NBLK, 256, 0, stream>>>(edge, edge + E, histG, boffs, binned, E, NB, chunk);
  k_C1<<<NB, 256, 0, stream>>>(binned, boffs, dis, n);
  k_C2<<<NB, 512, 0, stream>>>((const float2*)x, binned, boffs, dis,
                               (const float2*)scale, (const float2*)shift,
                               (float2*)out, n);
  k_gemm<<<(n + 31) / 32, 256, 0, stream>>>(out, (const float4*)x, W, bias,
                                            scale, shift, dis, n);
}

// Round 5
// 397.389 us; speedup vs baseline: 2.9440x; 1.1455x over previous
//
#include <hip/hip_runtime.h>

#define EPS_BN 1e-5f
#define C 128
#define CG 32     // float4 groups per 128-channel row
#define CAP 6144  // per-bucket edge capacity in LDS (mean 4096, sigma ~64)
#define NBLK 256  // partition blocks

__device__ inline unsigned bf16_rne(float f) {
  unsigned u = __float_as_uint(f);
  return (u + 0x7FFFu + ((u >> 16) & 1u)) >> 16;
}

// ---------------- init: zero BN accumulators ----------------------------------
__global__ void k_init(float* __restrict__ sums) {
  int i = blockIdx.x * blockDim.x + threadIdx.x;
  if (i < 256) sums[i] = 0.0f;
}

// ---------------- column sum / sumsq over rows --------------------------------
__global__ void k_stats(const float4* __restrict__ x4, float* __restrict__ sums, int n) {
  __shared__ float4 s_s[256];
  __shared__ float4 s_q[256];
  int t = threadIdx.x;
  int cg = t & 31;
  int rl = t >> 5;
  float4 s = make_float4(0.f, 0.f, 0.f, 0.f);
  float4 q = make_float4(0.f, 0.f, 0.f, 0.f);
  for (int r = blockIdx.x * 8 + rl; r < n; r += gridDim.x * 8) {
    float4 v = x4[(size_t)r * CG + cg];
    s.x += v.x; s.y += v.y; s.z += v.z; s.w += v.w;
    q.x += v.x * v.x; q.y += v.y * v.y; q.z += v.z * v.z; q.w += v.w * v.w;
  }
  s_s[t] = s; s_q[t] = q;
  __syncthreads();
  if (t < 32) {
    for (int j = 1; j < 8; ++j) {
      float4 a = s_s[t + 32 * j];
      float4 b = s_q[t + 32 * j];
      s.x += a.x; s.y += a.y; s.z += a.z; s.w += a.w;
      q.x += b.x; q.y += b.y; q.z += b.z; q.w += b.w;
    }
    atomicAdd(&sums[t * 4 + 0], s.x);
    atomicAdd(&sums[t * 4 + 1], s.y);
    atomicAdd(&sums[t * 4 + 2], s.z);
    atomicAdd(&sums[t * 4 + 3], s.w);
    atomicAdd(&sums[C + t * 4 + 0], q.x);
    atomicAdd(&sums[C + t * 4 + 1], q.y);
    atomicAdd(&sums[C + t * 4 + 2], q.z);
    atomicAdd(&sums[C + t * 4 + 3], q.w);
  }
}

// ---------------- fold BN into per-channel scale/shift ------------------------
__global__ void k_finalize(const float* __restrict__ sums,
                           const float* __restrict__ gamma,
                           const float* __restrict__ beta,
                           float* __restrict__ scale, float* __restrict__ shift,
                           int n) {
  int c = threadIdx.x;
  if (c < C) {
    float inv_n = 1.0f / (float)n;
    float mean = sums[c] * inv_n;
    float var = sums[C + c] * inv_n - mean * mean;
    float rstd = rsqrtf(var + EPS_BN);
    float sc = gamma[c] * rstd;
    scale[c] = sc;
    shift[c] = beta[c] - mean * sc;
  }
}

// ---------------- pass 1: per-block bucket histogram --------------------------
__global__ void k_hist(const int* __restrict__ col, int* __restrict__ histG,
                       int E, int NB, int chunk) {
  __shared__ int h[800];
  int b = blockIdx.x, t = threadIdx.x;
  for (int i = t; i < NB; i += 256) h[i] = 0;
  __syncthreads();
  int s = b * chunk, eend = min(E, s + chunk);
  for (int e = s + t; e < eend; e += 256) atomicAdd(&h[col[e] >> 7], 1);
  __syncthreads();
  for (int i = t; i < NB; i += 256) histG[b * NB + i] = h[i];
}

// ---------------- pass 2a: per-bucket scan over NBLK block counts -------------
__global__ void k_scanH(int* __restrict__ histG, int* __restrict__ btot, int NB) {
  __shared__ int sh[NBLK];
  int q = blockIdx.x, t = threadIdx.x;
  int v = histG[t * NB + q];
  sh[t] = v;
  __syncthreads();
  for (int off = 1; off < NBLK; off <<= 1) {
    int a = (t >= off) ? sh[t - off] : 0;
    __syncthreads();
    sh[t] += a;
    __syncthreads();
  }
  histG[t * NB + q] = sh[t] - v;  // exclusive within bucket
  if (t == NBLK - 1) btot[q] = sh[t];
}

// ---------------- pass 2b: scan bucket totals -> boffs ------------------------
__global__ void k_scanB(const int* __restrict__ btot, int* __restrict__ boffs,
                        int NB, int E) {
  __shared__ int sh[1024];
  int t = threadIdx.x;
  int v = (t < NB) ? btot[t] : 0;
  sh[t] = v;
  __syncthreads();
  for (int off = 1; off < 1024; off <<= 1) {
    int a = (t >= off) ? sh[t - off] : 0;
    __syncthreads();
    sh[t] += a;
    __syncthreads();
  }
  if (t < NB) boffs[t] = sh[t] - v;
  if (t == 0) boffs[NB] = E;
}

// ---------------- pass 3: scatter into disjoint per-(block,bucket) runs ------
__global__ void k_part(const int* __restrict__ row, const int* __restrict__ col,
                       const int* __restrict__ histG, const int* __restrict__ boffs,
                       unsigned* __restrict__ binned, int E, int NB, int chunk) {
  __shared__ int cur[800];
  int b = blockIdx.x, t = threadIdx.x;
  for (int i = t; i < NB; i += 256) cur[i] = boffs[i] + histG[b * NB + i];
  __syncthreads();
  int s = b * chunk, eend = min(E, s + chunk);
  for (int e = s + t; e < eend; e += 256) {
    int c = col[e];
    int pos = atomicAdd(&cur[c >> 7], 1);
    binned[pos] = ((unsigned)(c & 127) << 17) | (unsigned)row[e];
  }
}

// ---------------- C1: per-bucket degree count (LDS atomics) -> dis ------------
__global__ void k_C1(const unsigned* __restrict__ binned,
                     const int* __restrict__ boffs, float* __restrict__ dis,
                     int n) {
  __shared__ int cnt[128];
  int b = blockIdx.x, t = threadIdx.x;
  if (t < 128) cnt[t] = 0;
  __syncthreads();
  int s = boffs[b], tend = boffs[b + 1];
  for (int i = s + t; i < tend; i += 256) atomicAdd(&cnt[binned[i] >> 17], 1);
  __syncthreads();
  int node = b * 128 + t;
  if (t < 128 && node < n) dis[node] = rsqrtf((float)(cnt[t] + 1));
}

// ---------------- prep: y[r] = bf16x2( (x[r]*scale+shift) * dis[r] ) ----------
__global__ void k_prep(const float2* __restrict__ x2, const float* __restrict__ dis,
                       const float2* __restrict__ scale2,
                       const float2* __restrict__ shift2,
                       unsigned* __restrict__ y, int n) {
  int idx = blockIdx.x * blockDim.x + threadIdx.x;
  int r = idx >> 6;
  if (r >= n) return;
  int lane = idx & 63;
  float d = dis[r];
  float2 v = x2[(size_t)r * 64 + lane];
  float2 sc = scale2[lane], sh = shift2[lane];
  float y0 = (v.x * sc.x + sh.x) * d;
  float y1 = (v.y * sc.y + sh.y) * d;
  y[(size_t)r * 64 + lane] = (bf16_rne(y1) << 16) | bf16_rne(y0);
}

// ---------------- C2b: LDS-CSR build + bf16 gather-sum ------------------------
// out[c] = dis[c] * sum_e y[r_e]     (scale/shift/dis[r] pre-folded into y)
__global__ __launch_bounds__(512) void k_C2b(
    const unsigned* __restrict__ y, const unsigned* __restrict__ binned,
    const int* __restrict__ boffs, float2* __restrict__ out2, int n) {
  __shared__ int cnt[128];
  __shared__ int offs[128];
  __shared__ int cur[128];
  __shared__ int scn[128];
  __shared__ unsigned list[CAP];
  int b = blockIdx.x, t = threadIdx.x;
  if (t < 128) cnt[t] = 0;
  __syncthreads();
  int s = boffs[b], tend = boffs[b + 1];
  for (int i = s + t; i < tend; i += 512) atomicAdd(&cnt[binned[i] >> 17], 1);
  __syncthreads();
  if (t < 128) scn[t] = cnt[t];
  __syncthreads();
  for (int off = 1; off < 128; off <<= 1) {
    int a = (t >= off && t < 128) ? scn[t - off] : 0;
    __syncthreads();
    if (t < 128) scn[t] += a;
    __syncthreads();
  }
  if (t < 128) {
    offs[t] = scn[t] - cnt[t];
    cur[t] = scn[t] - cnt[t];
  }
  __syncthreads();
  for (int i = s + t; i < tend; i += 512) {
    unsigned e = binned[i];
    int pos = atomicAdd(&cur[e >> 17], 1);
    if (pos < CAP) list[pos] = e & 0x1FFFFu;
  }
  __syncthreads();
  int w = t >> 6, lane = t & 63;
  int bn = min(128, n - b * 128);
  for (int l = w; l < bn; l += 8) {
    int deg = cnt[l], base = offs[l];
    float2 a0 = make_float2(0.f, 0.f), a1 = make_float2(0.f, 0.f);
    float2 a2 = make_float2(0.f, 0.f), a3 = make_float2(0.f, 0.f);
    int i = 0;
    for (; i + 3 < deg; i += 4) {
      int r0 = list[base + i], r1 = list[base + i + 1];
      int r2 = list[base + i + 2], r3 = list[base + i + 3];
      unsigned u0 = y[(size_t)r0 * 64 + lane];
      unsigned u1 = y[(size_t)r1 * 64 + lane];
      unsigned u2 = y[(size_t)r2 * 64 + lane];
      unsigned u3 = y[(size_t)r3 * 64 + lane];
      a0.x += __uint_as_float(u0 << 16); a0.y += __uint_as_float(u0 & 0xFFFF0000u);
      a1.x += __uint_as_float(u1 << 16); a1.y += __uint_as_float(u1 & 0xFFFF0000u);
      a2.x += __uint_as_float(u2 << 16); a2.y += __uint_as_float(u2 & 0xFFFF0000u);
      a3.x += __uint_as_float(u3 << 16); a3.y += __uint_as_float(u3 & 0xFFFF0000u);
    }
    for (; i < deg; ++i) {
      unsigned u = y[(size_t)list[base + i] * 64 + lane];
      a0.x += __uint_as_float(u << 16); a0.y += __uint_as_float(u & 0xFFFF0000u);
    }
    float dc = rsqrtf((float)(deg + 1));
    float2 o;
    o.x = dc * (a0.x + a1.x + a2.x + a3.x);
    o.y = dc * (a0.y + a1.y + a2.y + a3.y);
    out2[(size_t)(b * 128 + l) * 64 + lane] = o;
  }
}

// ---------------- C2 fp32 fallback (R4 version, used if ws too small) ---------
__global__ __launch_bounds__(512) void k_C2(
    const float2* __restrict__ x2, const unsigned* __restrict__ binned,
    const int* __restrict__ boffs, const float* __restrict__ dis,
    const float2* __restrict__ scale2, const float2* __restrict__ shift2,
    float2* __restrict__ out2, int n) {
  __shared__ int cnt[128];
  __shared__ int offs[128];
  __shared__ int cur[128];
  __shared__ int scn[128];
  __shared__ unsigned list[CAP];
  int b = blockIdx.x, t = threadIdx.x;
  if (t < 128) cnt[t] = 0;
  __syncthreads();
  int s = boffs[b], tend = boffs[b + 1];
  for (int i = s + t; i < tend; i += 512) atomicAdd(&cnt[binned[i] >> 17], 1);
  __syncthreads();
  if (t < 128) scn[t] = cnt[t];
  __syncthreads();
  for (int off = 1; off < 128; off <<= 1) {
    int a = (t >= off && t < 128) ? scn[t - off] : 0;
    __syncthreads();
    if (t < 128) scn[t] += a;
    __syncthreads();
  }
  if (t < 128) {
    offs[t] = scn[t] - cnt[t];
    cur[t] = scn[t] - cnt[t];
  }
  __syncthreads();
  for (int i = s + t; i < tend; i += 512) {
    unsigned e = binned[i];
    int pos = atomicAdd(&cur[e >> 17], 1);
    if (pos < CAP) list[pos] = e & 0x1FFFFu;
  }
  __syncthreads();
  int w = t >> 6, lane = t & 63;
  int bn = min(128, n - b * 128);
  for (int l = w; l < bn; l += 8) {
    int deg = cnt[l], base = offs[l];
    float2 a0 = make_float2(0.f, 0.f), a1 = make_float2(0.f, 0.f);
    float sd0 = 0.f, sd1 = 0.f;
    int i = 0;
    for (; i + 1 < deg; i += 2) {
      int r0 = list[base + i], r1 = list[base + i + 1];
      float d0 = dis[r0], d1 = dis[r1];
      float2 v0 = x2[(size_t)r0 * 64 + lane];
      float2 v1 = x2[(size_t)r1 * 64 + lane];
      a0.x += v0.x * d0; a0.y += v0.y * d0; sd0 += d0;
      a1.x += v1.x * d1; a1.y += v1.y * d1; sd1 += d1;
    }
    if (i < deg) {
      int r = list[base + i];
      float d = dis[r];
      float2 v = x2[(size_t)r * 64 + lane];
      a0.x += v.x * d; a0.y += v.y * d; sd0 += d;
    }
    int node = b * 128 + l;
    float dc = dis[node];
    float2 sc = scale2[lane], sh = shift2[lane];
    float sd = sd0 + sd1;
    float2 o;
    o.x = dc * ((a0.x + a1.x) * sc.x + sd * sh.x);
    o.y = dc * ((a0.y + a1.y) * sc.y + sd * sh.y);
    out2[(size_t)node * 64 + lane] = o;
  }
}

// ---------------- in-place GEMM: out = relu((g + xn*invdeg) @ W + b) ----------
__global__ __launch_bounds__(256) void k_gemm(float* __restrict__ out,
                        const float4* __restrict__ x4,
                        const float* __restrict__ W,
                        const float* __restrict__ bias,
                        const float* __restrict__ scale,
                        const float* __restrict__ shift,
                        const float* __restrict__ dis, int n) {
  __shared__ float sW[64 * C];
  __shared__ float sG[32 * C];
  int t = threadIdx.x;
  int rowBase = blockIdx.x * 32;

  const float4* scale4 = (const float4*)scale;
  const float4* shift4 = (const float4*)shift;
  float4* sG4 = (float4*)sG;
  float4* sW4 = (float4*)sW;
  const float4* W4 = (const float4*)W;
  const float4* out4 = (const float4*)out;

  for (int i = t; i < 32 * CG; i += 256) {
    int r = i >> 5, g = i & 31;
    int rw = rowBase + r;
    float4 acc = make_float4(0.f, 0.f, 0.f, 0.f);
    if (rw < n) {
      acc = out4[(size_t)rw * CG + g];
      float4 xv = x4[(size_t)rw * CG + g];
      float d = dis[rw];
      float inv = d * d;
      float4 sc = scale4[g];
      float4 sh = shift4[g];
      acc.x += (xv.x * sc.x + sh.x) * inv;
      acc.y += (xv.y * sc.y + sh.y) * inv;
      acc.z += (xv.z * sc.z + sh.z) * inv;
      acc.w += (xv.w * sc.w + sh.w) * inv;
    }
    sG4[i] = acc;
  }

  int tx = t & 127;
  int ty = t >> 7;
  float acc[16];
#pragma unroll
  for (int i = 0; i < 16; ++i) acc[i] = 0.f;

  for (int kc = 0; kc < 2; ++kc) {
    for (int i = t; i < 64 * C / 4; i += 256) sW4[i] = W4[kc * 2048 + i];
    __syncthreads();
#pragma unroll 4
    for (int k = 0; k < 64; ++k) {
      float w = sW[k * C + tx];
#pragma unroll
      for (int rr = 0; rr < 16; ++rr)
        acc[rr] += sG[(rr * 2 + ty) * C + kc * 64 + k] * w;
    }
    __syncthreads();
  }

  float bv = bias[tx];
#pragma unroll
  for (int rr = 0; rr < 16; ++rr) {
    int rw = rowBase + rr * 2 + ty;
    if (rw < n) {
      float o = acc[rr] + bv;
      out[(size_t)rw * C + tx] = o > 0.f ? o : 0.f;
    }
  }
}

extern "C" void kernel_launch(void* const* d_in, const int* in_sizes, int n_in,
                              void* d_out, int out_size, void* d_ws, size_t ws_size,
                              hipStream_t stream) {
  const float* x = (const float*)d_in[0];
  const int* edge = (const int*)d_in[1];
  const float* gamma = (const float*)d_in[2];
  const float* beta = (const float*)d_in[3];
  const float* W = (const float*)d_in[4];
  const float* bias = (const float*)d_in[5];
  float* out = (float*)d_out;

  int n = in_sizes[0] / C;
  int E = in_sizes[1] / 2;
  int NB = (n + 127) / 128;           // buckets of 128 dst nodes (<=800)
  int chunk = (E + NBLK - 1) / NBLK;  // edges per partition block

  float* ws = (float*)d_ws;
  float* sums = ws;                      // 256 f
  float* scale = ws + 256;               // 128 f
  float* shift = ws + 384;               // 128 f
  float* dis = ws + 512;                 // n f
  int* btot = (int*)(ws + 512 + n);      // NB i
  int* boffs = btot + NB;                // NB+1 i
  int* histG = boffs + NB + 1;           // NBLK*NB i
  unsigned* binned = (unsigned*)(histG + (size_t)NBLK * NB);  // E u32
  unsigned* y = binned + E;              // n*64 u32 (bf16x2 rows)

  size_t need = (size_t)(512 + n + NB + NB + 1 + (size_t)NBLK * NB + E) +
                (size_t)n * 64;
  bool useBf16 = ws_size >= need * 4;

  k_init<<<1, 256, 0, stream>>>(sums);
  k_stats<<<256, 256, 0, stream>>>((const float4*)x, sums, n);
  k_finalize<<<1, 128, 0, stream>>>(sums, gamma, beta, scale, shift, n);
  k_hist<<<NBLK, 256, 0, stream>>>(edge + E, histG, E, NB, chunk);
  k_scanH<<<NB, NBLK, 0, stream>>>(histG, btot, NB);
  k_scanB<<<1, 1024, 0, stream>>>(btot, boffs, NB, E);
  k_part<<<NBLK, 256, 0, stream>>>(edge, edge + E, histG, boffs, binned, E, NB, chunk);
  k_C1<<<NB, 256, 0, stream>>>(binned, boffs, dis, n);
  if (useBf16) {
    k_prep<<<(n * 64 + 255) / 256, 256, 0, stream>>>(
        (const float2*)x, dis, (const float2*)scale, (const float2*)shift, y, n);
    k_C2b<<<NB, 512, 0, stream>>>(y, binned, boffs, (float2*)out, n);
  } else {
    k_C2<<<NB, 512, 0, stream>>>((const float2*)x, binned, boffs, dis,
                                 (const float2*)scale, (const float2*)shift,
                                 (float2*)out, n);
  }
  k_gemm<<<(n + 31) / 32, 256, 0, stream>>>(out, (const float4*)x, W, bias,
                                            scale, shift, dis, n);
}

// Round 6
// 376.896 us; speedup vs baseline: 3.1041x; 1.0544x over previous
//
#include <hip/hip_runtime.h>

#define EPS_BN 1e-5f
#define C 128
#define CG 32     // float4 groups per 128-channel row
#define CAP 6144  // per-bucket edge capacity in LDS (mean 4096, sigma ~64)
#define NBLK 256  // partition blocks

__device__ inline unsigned bf16_rne(float f) {
  unsigned u = __float_as_uint(f);
  return (u + 0x7FFFu + ((u >> 16) & 1u)) >> 16;
}

// ---------------- init: zero BN accumulators ----------------------------------
__global__ void k_init(float* __restrict__ sums) {
  int i = blockIdx.x * blockDim.x + threadIdx.x;
  if (i < 256) sums[i] = 0.0f;
}

// ---------------- column sum / sumsq over rows --------------------------------
__global__ void k_stats(const float4* __restrict__ x4, float* __restrict__ sums, int n) {
  __shared__ float4 s_s[256];
  __shared__ float4 s_q[256];
  int t = threadIdx.x;
  int cg = t & 31;
  int rl = t >> 5;
  float4 s = make_float4(0.f, 0.f, 0.f, 0.f);
  float4 q = make_float4(0.f, 0.f, 0.f, 0.f);
  for (int r = blockIdx.x * 8 + rl; r < n; r += gridDim.x * 8) {
    float4 v = x4[(size_t)r * CG + cg];
    s.x += v.x; s.y += v.y; s.z += v.z; s.w += v.w;
    q.x += v.x * v.x; q.y += v.y * v.y; q.z += v.z * v.z; q.w += v.w * v.w;
  }
  s_s[t] = s; s_q[t] = q;
  __syncthreads();
  if (t < 32) {
    for (int j = 1; j < 8; ++j) {
      float4 a = s_s[t + 32 * j];
      float4 b = s_q[t + 32 * j];
      s.x += a.x; s.y += a.y; s.z += a.z; s.w += a.w;
      q.x += b.x; q.y += b.y; q.z += b.z; q.w += b.w;
    }
    atomicAdd(&sums[t * 4 + 0], s.x);
    atomicAdd(&sums[t * 4 + 1], s.y);
    atomicAdd(&sums[t * 4 + 2], s.z);
    atomicAdd(&sums[t * 4 + 3], s.w);
    atomicAdd(&sums[C + t * 4 + 0], q.x);
    atomicAdd(&sums[C + t * 4 + 1], q.y);
    atomicAdd(&sums[C + t * 4 + 2], q.z);
    atomicAdd(&sums[C + t * 4 + 3], q.w);
  }
}

// ---------------- fold BN into per-channel scale/shift ------------------------
__global__ void k_finalize(const float* __restrict__ sums,
                           const float* __restrict__ gamma,
                           const float* __restrict__ beta,
                           float* __restrict__ scale, float* __restrict__ shift,
                           int n) {
  int c = threadIdx.x;
  if (c < C) {
    float inv_n = 1.0f / (float)n;
    float mean = sums[c] * inv_n;
    float var = sums[C + c] * inv_n - mean * mean;
    float rstd = rsqrtf(var + EPS_BN);
    float sc = gamma[c] * rstd;
    scale[c] = sc;
    shift[c] = beta[c] - mean * sc;
  }
}

// ---------------- pass 1: per-block bucket histogram --------------------------
__global__ void k_hist(const int* __restrict__ col, int* __restrict__ histG,
                       int E, int NB, int chunk) {
  __shared__ int h[800];
  int b = blockIdx.x, t = threadIdx.x;
  for (int i = t; i < NB; i += 256) h[i] = 0;
  __syncthreads();
  int s = b * chunk, eend = min(E, s + chunk);
  for (int e = s + t; e < eend; e += 256) atomicAdd(&h[col[e] >> 7], 1);
  __syncthreads();
  for (int i = t; i < NB; i += 256) histG[b * NB + i] = h[i];
}

// ---------------- pass 2a: per-bucket scan over NBLK block counts -------------
__global__ void k_scanH(int* __restrict__ histG, int* __restrict__ btot, int NB) {
  __shared__ int sh[NBLK];
  int q = blockIdx.x, t = threadIdx.x;
  int v = histG[t * NB + q];
  sh[t] = v;
  __syncthreads();
  for (int off = 1; off < NBLK; off <<= 1) {
    int a = (t >= off) ? sh[t - off] : 0;
    __syncthreads();
    sh[t] += a;
    __syncthreads();
  }
  histG[t * NB + q] = sh[t] - v;  // exclusive within bucket
  if (t == NBLK - 1) btot[q] = sh[t];
}

// ---------------- pass 2b: scan bucket totals -> boffs ------------------------
__global__ void k_scanB(const int* __restrict__ btot, int* __restrict__ boffs,
                        int NB, int E) {
  __shared__ int sh[1024];
  int t = threadIdx.x;
  int v = (t < NB) ? btot[t] : 0;
  sh[t] = v;
  __syncthreads();
  for (int off = 1; off < 1024; off <<= 1) {
    int a = (t >= off) ? sh[t - off] : 0;
    __syncthreads();
    sh[t] += a;
    __syncthreads();
  }
  if (t < NB) boffs[t] = sh[t] - v;
  if (t == 0) boffs[NB] = E;
}

// ---------------- pass 3: scatter into disjoint per-(block,bucket) runs ------
__global__ void k_part(const int* __restrict__ row, const int* __restrict__ col,
                       const int* __restrict__ histG, const int* __restrict__ boffs,
                       unsigned* __restrict__ binned, int E, int NB, int chunk) {
  __shared__ int cur[800];
  int b = blockIdx.x, t = threadIdx.x;
  for (int i = t; i < NB; i += 256) cur[i] = boffs[i] + histG[b * NB + i];
  __syncthreads();
  int s = b * chunk, eend = min(E, s + chunk);
  for (int e = s + t; e < eend; e += 256) {
    int c = col[e];
    int pos = atomicAdd(&cur[c >> 7], 1);
    binned[pos] = ((unsigned)(c & 127) << 17) | (unsigned)row[e];
  }
}

// ---------------- reorder: node-sort bucket in place; emit noffs + dis --------
__global__ __launch_bounds__(256) void k_reorder(
    unsigned* __restrict__ binned, const int* __restrict__ boffs,
    int* __restrict__ noffs, float* __restrict__ dis, int n, int E) {
  __shared__ int cnt[128];
  __shared__ int offs[128];
  __shared__ int cur[128];
  __shared__ int scn[128];
  __shared__ unsigned list[CAP];
  int b = blockIdx.x, t = threadIdx.x;
  if (t < 128) cnt[t] = 0;
  __syncthreads();
  int s = boffs[b], e = boffs[b + 1];
  // per-node degree count
  for (int i = s + t; i < e; i += 256) atomicAdd(&cnt[binned[i] >> 17], 1);
  __syncthreads();
  // exclusive scan of 128 counts
  if (t < 128) scn[t] = cnt[t];
  __syncthreads();
  for (int off = 1; off < 128; off <<= 1) {
    int a = (t >= off && t < 128) ? scn[t - off] : 0;
    __syncthreads();
    if (t < 128) scn[t] += a;
    __syncthreads();
  }
  if (t < 128) {
    offs[t] = scn[t] - cnt[t];
    cur[t] = scn[t] - cnt[t];
  }
  __syncthreads();
  // node-sorted fill in LDS
  for (int i = s + t; i < e; i += 256) {
    unsigned v = binned[i];
    int pos = atomicAdd(&cur[v >> 17], 1);
    if (pos < CAP) list[pos] = v & 0x1FFFFu;
  }
  __syncthreads();
  // write back in place (coalesced)
  int len = e - s;
  for (int i = t; i < len; i += 256) binned[s + i] = list[i];
  int node = b * 128 + t;
  if (t < 128 && node < n) {
    noffs[node] = s + offs[t];
    dis[node] = rsqrtf((float)(cnt[t] + 1));
  }
  if (b == 0 && t == 0) noffs[n] = E;
}

// ---------------- prep: y[r] = bf16x2( (x[r]*scale+shift) * dis[r] ) ----------
__global__ void k_prep(const float2* __restrict__ x2, const float* __restrict__ dis,
                       const float2* __restrict__ scale2,
                       const float2* __restrict__ shift2,
                       unsigned* __restrict__ y, int n) {
  int idx = blockIdx.x * blockDim.x + threadIdx.x;
  int r = idx >> 6;
  if (r >= n) return;
  int lane = idx & 63;
  float d = dis[r];
  float2 v = x2[(size_t)r * 64 + lane];
  float2 sc = scale2[lane], sh = shift2[lane];
  float y0 = (v.x * sc.x + sh.x) * d;
  float y1 = (v.y * sc.y + sh.y) * d;
  y[(size_t)r * 64 + lane] = (bf16_rne(y1) << 16) | bf16_rne(y0);
}

// ---------------- gather: one wave per dst node, no LDS -----------------------
// out[v] = dis[v] * sum_{e in [noffs[v],noffs[v+1])} y[lst[e]]
__global__ __launch_bounds__(256) void k_G(
    const unsigned* __restrict__ y, const unsigned* __restrict__ lst,
    const int* __restrict__ noffs, const float* __restrict__ dis,
    const float2* __restrict__ x2, const float2* __restrict__ scale2,
    const float2* __restrict__ shift2, float2* __restrict__ out2,
    int n, int useY) {
  int w = (blockIdx.x * blockDim.x + threadIdx.x) >> 6;
  if (w >= n) return;
  int lane = threadIdx.x & 63;
  int s = noffs[w], t = noffs[w + 1];
  float2 a0 = make_float2(0.f, 0.f), a1 = make_float2(0.f, 0.f);
  float2 a2 = make_float2(0.f, 0.f), a3 = make_float2(0.f, 0.f);
  if (useY) {
    int i = s;
    for (; i + 3 < t; i += 4) {
      int r0 = lst[i], r1 = lst[i + 1], r2 = lst[i + 2], r3 = lst[i + 3];
      unsigned u0 = y[(size_t)r0 * 64 + lane];
      unsigned u1 = y[(size_t)r1 * 64 + lane];
      unsigned u2 = y[(size_t)r2 * 64 + lane];
      unsigned u3 = y[(size_t)r3 * 64 + lane];
      a0.x += __uint_as_float(u0 << 16); a0.y += __uint_as_float(u0 & 0xFFFF0000u);
      a1.x += __uint_as_float(u1 << 16); a1.y += __uint_as_float(u1 & 0xFFFF0000u);
      a2.x += __uint_as_float(u2 << 16); a2.y += __uint_as_float(u2 & 0xFFFF0000u);
      a3.x += __uint_as_float(u3 << 16); a3.y += __uint_as_float(u3 & 0xFFFF0000u);
    }
    for (; i < t; ++i) {
      unsigned u = y[(size_t)lst[i] * 64 + lane];
      a0.x += __uint_as_float(u << 16); a0.y += __uint_as_float(u & 0xFFFF0000u);
    }
    float dc = dis[w];
    float2 o;
    o.x = dc * (a0.x + a1.x + a2.x + a3.x);
    o.y = dc * (a0.y + a1.y + a2.y + a3.y);
    out2[(size_t)w * 64 + lane] = o;
  } else {
    // fp32 fallback: fold scale/shift/dis on the fly
    float sd = 0.f;
    for (int i = s; i < t; ++i) {
      int r = lst[i];
      float d = dis[r];
      float2 v = x2[(size_t)r * 64 + lane];
      a0.x += v.x * d; a0.y += v.y * d; sd += d;
    }
    float dc = dis[w];
    float2 sc = scale2[lane], sh = shift2[lane];
    float2 o;
    o.x = dc * (a0.x * sc.x + sd * sh.x);
    o.y = dc * (a0.y * sc.y + sd * sh.y);
    out2[(size_t)w * 64 + lane] = o;
  }
}

// ---------------- in-place GEMM: out = relu((g + xn*invdeg) @ W + b) ----------
__global__ __launch_bounds__(256) void k_gemm(float* __restrict__ out,
                        const float4* __restrict__ x4,
                        const float* __restrict__ W,
                        const float* __restrict__ bias,
                        const float* __restrict__ scale,
                        const float* __restrict__ shift,
                        const float* __restrict__ dis, int n) {
  __shared__ float sW[64 * C];
  __shared__ float sG[32 * C];
  int t = threadIdx.x;
  int rowBase = blockIdx.x * 32;

  const float4* scale4 = (const float4*)scale;
  const float4* shift4 = (const float4*)shift;
  float4* sG4 = (float4*)sG;
  float4* sW4 = (float4*)sW;
  const float4* W4 = (const float4*)W;
  const float4* out4 = (const float4*)out;

  for (int i = t; i < 32 * CG; i += 256) {
    int r = i >> 5, g = i & 31;
    int rw = rowBase + r;
    float4 acc = make_float4(0.f, 0.f, 0.f, 0.f);
    if (rw < n) {
      acc = out4[(size_t)rw * CG + g];
      float4 xv = x4[(size_t)rw * CG + g];
      float d = dis[rw];
      float inv = d * d;
      float4 sc = scale4[g];
      float4 sh = shift4[g];
      acc.x += (xv.x * sc.x + sh.x) * inv;
      acc.y += (xv.y * sc.y + sh.y) * inv;
      acc.z += (xv.z * sc.z + sh.z) * inv;
      acc.w += (xv.w * sc.w + sh.w) * inv;
    }
    sG4[i] = acc;
  }

  int tx = t & 127;
  int ty = t >> 7;
  float acc[16];
#pragma unroll
  for (int i = 0; i < 16; ++i) acc[i] = 0.f;

  for (int kc = 0; kc < 2; ++kc) {
    for (int i = t; i < 64 * C / 4; i += 256) sW4[i] = W4[kc * 2048 + i];
    __syncthreads();
#pragma unroll 4
    for (int k = 0; k < 64; ++k) {
      float w = sW[k * C + tx];
#pragma unroll
      for (int rr = 0; rr < 16; ++rr)
        acc[rr] += sG[(rr * 2 + ty) * C + kc * 64 + k] * w;
    }
    __syncthreads();
  }

  float bv = bias[tx];
#pragma unroll
  for (int rr = 0; rr < 16; ++rr) {
    int rw = rowBase + rr * 2 + ty;
    if (rw < n) {
      float o = acc[rr] + bv;
      out[(size_t)rw * C + tx] = o > 0.f ? o : 0.f;
    }
  }
}

extern "C" void kernel_launch(void* const* d_in, const int* in_sizes, int n_in,
                              void* d_out, int out_size, void* d_ws, size_t ws_size,
                              hipStream_t stream) {
  const float* x = (const float*)d_in[0];
  const int* edge = (const int*)d_in[1];
  const float* gamma = (const float*)d_in[2];
  const float* beta = (const float*)d_in[3];
  const float* W = (const float*)d_in[4];
  const float* bias = (const float*)d_in[5];
  float* out = (float*)d_out;

  int n = in_sizes[0] / C;
  int E = in_sizes[1] / 2;
  int NB = (n + 127) / 128;           // buckets of 128 dst nodes (<=800)
  int chunk = (E + NBLK - 1) / NBLK;  // edges per partition block

  float* ws = (float*)d_ws;
  float* sums = ws;                      // 256 f
  float* scale = ws + 256;               // 128 f
  float* shift = ws + 384;               // 128 f
  float* dis = ws + 512;                 // n f
  int* btot = (int*)(ws + 512 + n);      // NB i
  int* boffs = btot + NB;                // NB+1 i
  int* noffs = boffs + NB + 1;           // n+1 i
  int* histG = noffs + n + 1;            // NBLK*NB i
  unsigned* binned = (unsigned*)(histG + (size_t)NBLK * NB);  // E u32
  unsigned* y = binned + E;              // n*64 u32 (bf16x2 rows)

  size_t need = (size_t)512 + n + NB + (NB + 1) + (n + 1) +
                (size_t)NBLK * NB + E + (size_t)n * 64;
  int useY = (ws_size >= need * 4) ? 1 : 0;

  k_init<<<1, 256, 0, stream>>>(sums);
  k_stats<<<256, 256, 0, stream>>>((const float4*)x, sums, n);
  k_finalize<<<1, 128, 0, stream>>>(sums, gamma, beta, scale, shift, n);
  k_hist<<<NBLK, 256, 0, stream>>>(edge + E, histG, E, NB, chunk);
  k_scanH<<<NB, NBLK, 0, stream>>>(histG, btot, NB);
  k_scanB<<<1, 1024, 0, stream>>>(btot, boffs, NB, E);
  k_part<<<NBLK, 256, 0, stream>>>(edge, edge + E, histG, boffs, binned, E, NB, chunk);
  k_reorder<<<NB, 256, 0, stream>>>(binned, boffs, noffs, dis, n, E);
  if (useY) {
    k_prep<<<(n * 64 + 255) / 256, 256, 0, stream>>>(
        (const float2*)x, dis, (const float2*)scale, (const float2*)shift, y, n);
  }
  k_G<<<(n * 64 + 255) / 256, 256, 0, stream>>>(
      y, binned, noffs, dis, (const float2*)x, (const float2*)scale,
      (const float2*)shift, (float2*)out, n, useY);
  k_gemm<<<(n + 31) / 32, 256, 0, stream>>>(out, (const float4*)x, W, bias,
                                            scale, shift, dis, n);
}

// Round 7
// 349.012 us; speedup vs baseline: 3.3521x; 1.0799x over previous
//
#include <hip/hip_runtime.h>

#define EPS_BN 1e-5f
#define C 128
#define CG 32     // float4 groups per 128-channel row
#define CAP 6144  // per-bucket edge capacity in LDS (mean 4096, sigma ~64)
#define NBLK 256  // partition blocks

typedef __attribute__((ext_vector_type(8))) short bf16x8;
typedef __attribute__((ext_vector_type(4))) float f32x4;

__device__ inline unsigned bf16_rne(float f) {
  unsigned u = __float_as_uint(f);
  return (u + 0x7FFFu + ((u >> 16) & 1u)) >> 16;
}
__device__ inline float bf16_f(unsigned h) { return __uint_as_float(h << 16); }

// ---------------- init: zero BN accumulators ----------------------------------
__global__ void k_init(float* __restrict__ sums) {
  int i = blockIdx.x * blockDim.x + threadIdx.x;
  if (i < 256) sums[i] = 0.0f;
}

// ---------------- column sum / sumsq over rows --------------------------------
__global__ void k_stats(const float4* __restrict__ x4, float* __restrict__ sums, int n) {
  __shared__ float4 s_s[256];
  __shared__ float4 s_q[256];
  int t = threadIdx.x;
  int cg = t & 31;
  int rl = t >> 5;
  float4 s = make_float4(0.f, 0.f, 0.f, 0.f);
  float4 q = make_float4(0.f, 0.f, 0.f, 0.f);
  for (int r = blockIdx.x * 8 + rl; r < n; r += gridDim.x * 8) {
    float4 v = x4[(size_t)r * CG + cg];
    s.x += v.x; s.y += v.y; s.z += v.z; s.w += v.w;
    q.x += v.x * v.x; q.y += v.y * v.y; q.z += v.z * v.z; q.w += v.w * v.w;
  }
  s_s[t] = s; s_q[t] = q;
  __syncthreads();
  if (t < 32) {
    for (int j = 1; j < 8; ++j) {
      float4 a = s_s[t + 32 * j];
      float4 b = s_q[t + 32 * j];
      s.x += a.x; s.y += a.y; s.z += a.z; s.w += a.w;
      q.x += b.x; q.y += b.y; q.z += b.z; q.w += b.w;
    }
    atomicAdd(&sums[t * 4 + 0], s.x);
    atomicAdd(&sums[t * 4 + 1], s.y);
    atomicAdd(&sums[t * 4 + 2], s.z);
    atomicAdd(&sums[t * 4 + 3], s.w);
    atomicAdd(&sums[C + t * 4 + 0], q.x);
    atomicAdd(&sums[C + t * 4 + 1], q.y);
    atomicAdd(&sums[C + t * 4 + 2], q.z);
    atomicAdd(&sums[C + t * 4 + 3], q.w);
  }
}

// ---------------- fold BN into per-channel scale/shift ------------------------
__global__ void k_finalize(const float* __restrict__ sums,
                           const float* __restrict__ gamma,
                           const float* __restrict__ beta,
                           float* __restrict__ scale, float* __restrict__ shift,
                           int n) {
  int c = threadIdx.x;
  if (c < C) {
    float inv_n = 1.0f / (float)n;
    float mean = sums[c] * inv_n;
    float var = sums[C + c] * inv_n - mean * mean;
    float rstd = rsqrtf(var + EPS_BN);
    float sc = gamma[c] * rstd;
    scale[c] = sc;
    shift[c] = beta[c] - mean * sc;
  }
}

// ---------------- pass 1: per-block bucket histogram --------------------------
__global__ void k_hist(const int* __restrict__ col, int* __restrict__ histG,
                       int E, int NB, int chunk) {
  __shared__ int h[800];
  int b = blockIdx.x, t = threadIdx.x;
  for (int i = t; i < NB; i += 256) h[i] = 0;
  __syncthreads();
  int s = b * chunk, eend = min(E, s + chunk);
  for (int e = s + t; e < eend; e += 256) atomicAdd(&h[col[e] >> 7], 1);
  __syncthreads();
  for (int i = t; i < NB; i += 256) histG[b * NB + i] = h[i];
}

// ---------------- pass 2a: per-bucket scan over NBLK block counts -------------
__global__ void k_scanH(int* __restrict__ histG, int* __restrict__ btot, int NB) {
  __shared__ int sh[NBLK];
  int q = blockIdx.x, t = threadIdx.x;
  int v = histG[t * NB + q];
  sh[t] = v;
  __syncthreads();
  for (int off = 1; off < NBLK; off <<= 1) {
    int a = (t >= off) ? sh[t - off] : 0;
    __syncthreads();
    sh[t] += a;
    __syncthreads();
  }
  histG[t * NB + q] = sh[t] - v;  // exclusive within bucket
  if (t == NBLK - 1) btot[q] = sh[t];
}

// ---------------- pass 2b: scan bucket totals -> boffs ------------------------
__global__ void k_scanB(const int* __restrict__ btot, int* __restrict__ boffs,
                        int NB, int E) {
  __shared__ int sh[1024];
  int t = threadIdx.x;
  int v = (t < NB) ? btot[t] : 0;
  sh[t] = v;
  __syncthreads();
  for (int off = 1; off < 1024; off <<= 1) {
    int a = (t >= off) ? sh[t - off] : 0;
    __syncthreads();
    sh[t] += a;
    __syncthreads();
  }
  if (t < NB) boffs[t] = sh[t] - v;
  if (t == 0) boffs[NB] = E;
}

// ---------------- pass 3: scatter into disjoint per-(block,bucket) runs ------
__global__ void k_part(const int* __restrict__ row, const int* __restrict__ col,
                       const int* __restrict__ histG, const int* __restrict__ boffs,
                       unsigned* __restrict__ binned, int E, int NB, int chunk) {
  __shared__ int cur[800];
  int b = blockIdx.x, t = threadIdx.x;
  for (int i = t; i < NB; i += 256) cur[i] = boffs[i] + histG[b * NB + i];
  __syncthreads();
  int s = b * chunk, eend = min(E, s + chunk);
  for (int e = s + t; e < eend; e += 256) {
    int c = col[e];
    int pos = atomicAdd(&cur[c >> 7], 1);
    binned[pos] = ((unsigned)(c & 127) << 17) | (unsigned)row[e];
  }
}

// ---------------- reorder: node-sort bucket in place; emit noffs + dis --------
__global__ __launch_bounds__(256) void k_reorder(
    unsigned* __restrict__ binned, const int* __restrict__ boffs,
    int* __restrict__ noffs, float* __restrict__ dis, int n, int E) {
  __shared__ int cnt[128];
  __shared__ int offs[128];
  __shared__ int cur[128];
  __shared__ int scn[128];
  __shared__ unsigned list[CAP];
  int b = blockIdx.x, t = threadIdx.x;
  if (t < 128) cnt[t] = 0;
  __syncthreads();
  int s = boffs[b], e = boffs[b + 1];
  for (int i = s + t; i < e; i += 256) atomicAdd(&cnt[binned[i] >> 17], 1);
  __syncthreads();
  if (t < 128) scn[t] = cnt[t];
  __syncthreads();
  for (int off = 1; off < 128; off <<= 1) {
    int a = (t >= off && t < 128) ? scn[t - off] : 0;
    __syncthreads();
    if (t < 128) scn[t] += a;
    __syncthreads();
  }
  if (t < 128) {
    offs[t] = scn[t] - cnt[t];
    cur[t] = scn[t] - cnt[t];
  }
  __syncthreads();
  for (int i = s + t; i < e; i += 256) {
    unsigned v = binned[i];
    int pos = atomicAdd(&cur[v >> 17], 1);
    if (pos < CAP) list[pos] = v & 0x1FFFFu;
  }
  __syncthreads();
  int len = e - s;
  for (int i = t; i < len; i += 256) binned[s + i] = list[i];
  int node = b * 128 + t;
  if (t < 128 && node < n) {
    noffs[node] = s + offs[t];
    dis[node] = rsqrtf((float)(cnt[t] + 1));
  }
  if (b == 0 && t == 0) noffs[n] = E;
}

// ---------------- prep: y[r] = bf16x2( (x[r]*scale+shift) * dis[r] ) ----------
__global__ void k_prep(const float2* __restrict__ x2, const float* __restrict__ dis,
                       const float2* __restrict__ scale2,
                       const float2* __restrict__ shift2,
                       unsigned* __restrict__ y, int n) {
  int idx = blockIdx.x * blockDim.x + threadIdx.x;
  int r = idx >> 6;
  if (r >= n) return;
  int lane = idx & 63;
  float d = dis[r];
  float2 v = x2[(size_t)r * 64 + lane];
  float2 sc = scale2[lane], sh = shift2[lane];
  float y0 = (v.x * sc.x + sh.x) * d;
  float y1 = (v.y * sc.y + sh.y) * d;
  y[(size_t)r * 64 + lane] = (bf16_rne(y1) << 16) | bf16_rne(y0);
}

// ---------------- G2: gather + self-loop, emit split-bf16 g -------------------
// g[v] = dis[v] * ( sum_e y[r_e] + y[v] )
__global__ __launch_bounds__(256) void k_G2(
    const unsigned* __restrict__ y, const unsigned* __restrict__ lst,
    const int* __restrict__ noffs, const float* __restrict__ dis,
    unsigned* __restrict__ ghi, unsigned* __restrict__ glo, int n) {
  int w = (blockIdx.x * blockDim.x + threadIdx.x) >> 6;
  if (w >= n) return;
  int lane = threadIdx.x & 63;
  int s = noffs[w], t = noffs[w + 1];
  float2 a0 = make_float2(0.f, 0.f), a1 = make_float2(0.f, 0.f);
  float2 a2 = make_float2(0.f, 0.f), a3 = make_float2(0.f, 0.f);
  int i = s;
  for (; i + 3 < t; i += 4) {
    int r0 = lst[i], r1 = lst[i + 1], r2 = lst[i + 2], r3 = lst[i + 3];
    unsigned u0 = y[(size_t)r0 * 64 + lane];
    unsigned u1 = y[(size_t)r1 * 64 + lane];
    unsigned u2 = y[(size_t)r2 * 64 + lane];
    unsigned u3 = y[(size_t)r3 * 64 + lane];
    a0.x += __uint_as_float(u0 << 16); a0.y += __uint_as_float(u0 & 0xFFFF0000u);
    a1.x += __uint_as_float(u1 << 16); a1.y += __uint_as_float(u1 & 0xFFFF0000u);
    a2.x += __uint_as_float(u2 << 16); a2.y += __uint_as_float(u2 & 0xFFFF0000u);
    a3.x += __uint_as_float(u3 << 16); a3.y += __uint_as_float(u3 & 0xFFFF0000u);
  }
  for (; i < t; ++i) {
    unsigned u = y[(size_t)lst[i] * 64 + lane];
    a0.x += __uint_as_float(u << 16); a0.y += __uint_as_float(u & 0xFFFF0000u);
  }
  unsigned uw = y[(size_t)w * 64 + lane];  // self loop
  a0.x += __uint_as_float(uw << 16); a0.y += __uint_as_float(uw & 0xFFFF0000u);
  float dc = dis[w];
  float gx = dc * (a0.x + a1.x + a2.x + a3.x);
  float gy = dc * (a0.y + a1.y + a2.y + a3.y);
  unsigned hx = bf16_rne(gx), hy = bf16_rne(gy);
  unsigned lx = bf16_rne(gx - bf16_f(hx)), ly = bf16_rne(gy - bf16_f(hy));
  size_t o = (size_t)w * 64 + lane;
  ghi[o] = (hy << 16) | hx;
  glo[o] = (ly << 16) | lx;
}

// ---------------- MFMA GEMM: out = relu((ghi+glo) @ W + b) --------------------
__global__ __launch_bounds__(256) void k_gemmM(
    const unsigned* __restrict__ ghi, const unsigned* __restrict__ glo,
    const float* __restrict__ W, const float* __restrict__ bias,
    float* __restrict__ out, int n) {
  __shared__ __align__(16) unsigned short sGh[64][136];
  __shared__ __align__(16) unsigned short sGl[64][136];
  __shared__ __align__(16) unsigned short sWt[128][136];
  int t = threadIdx.x;
  int rowBase = blockIdx.x * 64;
  // stage W transposed as bf16: sWt[col][k]
  for (int i = t; i < 16384; i += 256) {
    int k = i >> 7, c = i & 127;
    sWt[c][k] = (unsigned short)bf16_rne(W[i]);
  }
  // stage G hi/lo tiles (64 rows x 128 ch = 64 u32/row)
  for (int i = t; i < 4096; i += 256) {
    int r = i >> 6, c = i & 63;
    int rw = rowBase + r;
    unsigned uh = 0, ul = 0;
    if (rw < n) {
      uh = ghi[(size_t)rw * 64 + c];
      ul = glo[(size_t)rw * 64 + c];
    }
    *(unsigned*)&sGh[r][c * 2] = uh;
    *(unsigned*)&sGl[r][c * 2] = ul;
  }
  __syncthreads();
  int w = t >> 6, l = t & 63;
  int m16 = l & 15, kb = l >> 4;
  int rtile = w * 16;
  f32x4 acc[8];
#pragma unroll
  for (int i = 0; i < 8; ++i) acc[i] = (f32x4){0.f, 0.f, 0.f, 0.f};
#pragma unroll
  for (int kt = 0; kt < 4; ++kt) {
    int koff = kt * 32 + kb * 8;
    bf16x8 ah = *(const bf16x8*)&sGh[rtile + m16][koff];
    bf16x8 al = *(const bf16x8*)&sGl[rtile + m16][koff];
#pragma unroll
    for (int nt = 0; nt < 8; ++nt) {
      bf16x8 bb = *(const bf16x8*)&sWt[nt * 16 + m16][koff];
      acc[nt] = __builtin_amdgcn_mfma_f32_16x16x32_bf16(ah, bb, acc[nt], 0, 0, 0);
      acc[nt] = __builtin_amdgcn_mfma_f32_16x16x32_bf16(al, bb, acc[nt], 0, 0, 0);
    }
  }
#pragma unroll
  for (int nt = 0; nt < 8; ++nt) {
    int colc = nt * 16 + m16;
    float bv = bias[colc];
#pragma unroll
    for (int reg = 0; reg < 4; ++reg) {
      int row = rowBase + rtile + kb * 4 + reg;
      if (row < n) {
        float o = acc[nt][reg] + bv;
        out[(size_t)row * C + colc] = fmaxf(o, 0.f);
      }
    }
  }
}

// ---------------- old gather (fallback): writes fp32 out ----------------------
__global__ __launch_bounds__(256) void k_G(
    const unsigned* __restrict__ y, const unsigned* __restrict__ lst,
    const int* __restrict__ noffs, const float* __restrict__ dis,
    const float2* __restrict__ x2, const float2* __restrict__ scale2,
    const float2* __restrict__ shift2, float2* __restrict__ out2,
    int n, int useY) {
  int w = (blockIdx.x * blockDim.x + threadIdx.x) >> 6;
  if (w >= n) return;
  int lane = threadIdx.x & 63;
  int s = noffs[w], t = noffs[w + 1];
  float2 a0 = make_float2(0.f, 0.f), a1 = make_float2(0.f, 0.f);
  float2 a2 = make_float2(0.f, 0.f), a3 = make_float2(0.f, 0.f);
  if (useY) {
    int i = s;
    for (; i + 3 < t; i += 4) {
      int r0 = lst[i], r1 = lst[i + 1], r2 = lst[i + 2], r3 = lst[i + 3];
      unsigned u0 = y[(size_t)r0 * 64 + lane];
      unsigned u1 = y[(size_t)r1 * 64 + lane];
      unsigned u2 = y[(size_t)r2 * 64 + lane];
      unsigned u3 = y[(size_t)r3 * 64 + lane];
      a0.x += __uint_as_float(u0 << 16); a0.y += __uint_as_float(u0 & 0xFFFF0000u);
      a1.x += __uint_as_float(u1 << 16); a1.y += __uint_as_float(u1 & 0xFFFF0000u);
      a2.x += __uint_as_float(u2 << 16); a2.y += __uint_as_float(u2 & 0xFFFF0000u);
      a3.x += __uint_as_float(u3 << 16); a3.y += __uint_as_float(u3 & 0xFFFF0000u);
    }
    for (; i < t; ++i) {
      unsigned u = y[(size_t)lst[i] * 64 + lane];
      a0.x += __uint_as_float(u << 16); a0.y += __uint_as_float(u & 0xFFFF0000u);
    }
    float dc = dis[w];
    float2 o;
    o.x = dc * (a0.x + a1.x + a2.x + a3.x);
    o.y = dc * (a0.y + a1.y + a2.y + a3.y);
    out2[(size_t)w * 64 + lane] = o;
  } else {
    float sd = 0.f;
    for (int i = s; i < t; ++i) {
      int r = lst[i];
      float d = dis[r];
      float2 v = x2[(size_t)r * 64 + lane];
      a0.x += v.x * d; a0.y += v.y * d; sd += d;
    }
    float dc = dis[w];
    float2 sc = scale2[lane], sh = shift2[lane];
    float2 o;
    o.x = dc * (a0.x * sc.x + sd * sh.x);
    o.y = dc * (a0.y * sc.y + sd * sh.y);
    out2[(size_t)w * 64 + lane] = o;
  }
}

// ---------------- old scalar GEMM (fallback) ----------------------------------
__global__ __launch_bounds__(256) void k_gemm(float* __restrict__ out,
                        const float4* __restrict__ x4,
                        const float* __restrict__ W,
                        const float* __restrict__ bias,
                        const float* __restrict__ scale,
                        const float* __restrict__ shift,
                        const float* __restrict__ dis, int n) {
  __shared__ float sW[64 * C];
  __shared__ float sG[32 * C];
  int t = threadIdx.x;
  int rowBase = blockIdx.x * 32;

  const float4* scale4 = (const float4*)scale;
  const float4* shift4 = (const float4*)shift;
  float4* sG4 = (float4*)sG;
  float4* sW4 = (float4*)sW;
  const float4* W4 = (const float4*)W;
  const float4* out4 = (const float4*)out;

  for (int i = t; i < 32 * CG; i += 256) {
    int r = i >> 5, g = i & 31;
    int rw = rowBase + r;
    float4 acc = make_float4(0.f, 0.f, 0.f, 0.f);
    if (rw < n) {
      acc = out4[(size_t)rw * CG + g];
      float4 xv = x4[(size_t)rw * CG + g];
      float d = dis[rw];
      float inv = d * d;
      float4 sc = scale4[g];
      float4 sh = shift4[g];
      acc.x += (xv.x * sc.x + sh.x) * inv;
      acc.y += (xv.y * sc.y + sh.y) * inv;
      acc.z += (xv.z * sc.z + sh.z) * inv;
      acc.w += (xv.w * sc.w + sh.w) * inv;
    }
    sG4[i] = acc;
  }

  int tx = t & 127;
  int ty = t >> 7;
  float acc[16];
#pragma unroll
  for (int i = 0; i < 16; ++i) acc[i] = 0.f;

  for (int kc = 0; kc < 2; ++kc) {
    for (int i = t; i < 64 * C / 4; i += 256) sW4[i] = W4[kc * 2048 + i];
    __syncthreads();
#pragma unroll 4
    for (int k = 0; k < 64; ++k) {
      float w = sW[k * C + tx];
#pragma unroll
      for (int rr = 0; rr < 16; ++rr)
        acc[rr] += sG[(rr * 2 + ty) * C + kc * 64 + k] * w;
    }
    __syncthreads();
  }

  float bv = bias[tx];
#pragma unroll
  for (int rr = 0; rr < 16; ++rr) {
    int rw = rowBase + rr * 2 + ty;
    if (rw < n) {
      float o = acc[rr] + bv;
      out[(size_t)rw * C + tx] = o > 0.f ? o : 0.f;
    }
  }
}

extern "C" void kernel_launch(void* const* d_in, const int* in_sizes, int n_in,
                              void* d_out, int out_size, void* d_ws, size_t ws_size,
                              hipStream_t stream) {
  const float* x = (const float*)d_in[0];
  const int* edge = (const int*)d_in[1];
  const float* gamma = (const float*)d_in[2];
  const float* beta = (const float*)d_in[3];
  const float* W = (const float*)d_in[4];
  const float* bias = (const float*)d_in[5];
  float* out = (float*)d_out;

  int n = in_sizes[0] / C;
  int E = in_sizes[1] / 2;
  int NB = (n + 127) / 128;           // buckets of 128 dst nodes (<=800)
  int chunk = (E + NBLK - 1) / NBLK;  // edges per partition block

  float* ws = (float*)d_ws;
  float* sums = ws;                      // 256 f
  float* scale = ws + 256;               // 128 f
  float* shift = ws + 384;               // 128 f
  float* dis = ws + 512;                 // n f
  int* btot = (int*)(ws + 512 + n);      // NB i
  int* boffs = btot + NB;                // NB+1 i
  int* noffs = boffs + NB + 1;           // n+1 i
  int* histG = noffs + n + 1;            // NBLK*NB i
  unsigned* binned = (unsigned*)(histG + (size_t)NBLK * NB);  // E u32
  unsigned* y = binned + E;              // n*64 u32 (bf16x2 rows)
  unsigned* ghi = y + (size_t)n * 64;    // n*64 u32
  unsigned* glo = ghi + (size_t)n * 64;  // n*64 u32

  size_t base = (size_t)512 + n + NB + (NB + 1) + (n + 1) +
                (size_t)NBLK * NB + E;
  size_t need_old = base + (size_t)n * 64;
  size_t need_new = base + (size_t)n * 64 * 3;
  int mode = (ws_size >= need_new * 4) ? 2 : (ws_size >= need_old * 4) ? 1 : 0;

  k_init<<<1, 256, 0, stream>>>(sums);
  k_stats<<<256, 256, 0, stream>>>((const float4*)x, sums, n);
  k_finalize<<<1, 128, 0, stream>>>(sums, gamma, beta, scale, shift, n);
  k_hist<<<NBLK, 256, 0, stream>>>(edge + E, histG, E, NB, chunk);
  k_scanH<<<NB, NBLK, 0, stream>>>(histG, btot, NB);
  k_scanB<<<1, 1024, 0, stream>>>(btot, boffs, NB, E);
  k_part<<<NBLK, 256, 0, stream>>>(edge, edge + E, histG, boffs, binned, E, NB, chunk);
  k_reorder<<<NB, 256, 0, stream>>>(binned, boffs, noffs, dis, n, E);
  if (mode >= 1) {
    k_prep<<<(n * 64 + 255) / 256, 256, 0, stream>>>(
        (const float2*)x, dis, (const float2*)scale, (const float2*)shift, y, n);
  }
  if (mode == 2) {
    k_G2<<<(n * 64 + 255) / 256, 256, 0, stream>>>(y, binned, noffs, dis,
                                                   ghi, glo, n);
    k_gemmM<<<(n + 63) / 64, 256, 0, stream>>>(ghi, glo, W, bias, out, n);
  } else {
    k_G<<<(n * 64 + 255) / 256, 256, 0, stream>>>(
        y, binned, noffs, dis, (const float2*)x, (const float2*)scale,
        (const float2*)shift, (float2*)out, n, mode);
    k_gemm<<<(n + 31) / 32, 256, 0, stream>>>(out, (const float4*)x, W, bias,
                                              scale, shift, dis, n);
  }
}